// Round 1
// 678.488 us; speedup vs baseline: 1.0091x; 1.0091x over previous
//
#include <hip/hip_runtime.h>
#include <math.h>

#define NUM_LAYERS 10

// LDS layout: 64 rows x 60 floats, row stride padded to 61.
// Read pattern: lane t reads lds_af[61*t + c] -> bank (29*t + c) % 32,
// gcd(29,32)=1 -> 2 lanes/bank across wave64 = conflict-free (m136).
#define AF_PAD 61

__device__ __forceinline__ float det3(const float* __restrict__ W) {
    return W[0] * (W[4] * W[8] - W[5] * W[7])
         - W[1] * (W[3] * W[8] - W[5] * W[6])
         + W[2] * (W[3] * W[7] - W[4] * W[6]);
}

// Uniform part of total_log_det: sum of log|det W_i| + log|det lastW|
// plus the constant -(D/2)*log(2*pi) from the base-density term.
__device__ __forceinline__ float const_logdet(const float* __restrict__ Ws,
                                              const float* __restrict__ lastW) {
    float cld = 0.0f;
#pragma unroll
    for (int i = 0; i < NUM_LAYERS; ++i) {
        cld += __logf(fabsf(det3(Ws + i * 9)));
    }
    cld += __logf(fabsf(det3(lastW)));
    cld += -1.5f * 1.8378770664093453f;   // -(3/2)*log(2*pi)
    return cld;
}

// Tiny prep kernel: computes the wave-uniform log-det constant ONCE,
// instead of every one of the 2M threads doing 11 logf + ~190 FLOPs.
__global__ void prep_kernel(const float* __restrict__ Ws,
                            const float* __restrict__ lastW,
                            float* __restrict__ out) {
    *out = const_logdet(Ws, lastW);
}

__global__ __launch_bounds__(64) void flow_kernel(
    const float* __restrict__ x,
    const float* __restrict__ affine,   // (N, 60)
    const float* __restrict__ Ws,       // (10, 3, 3)
    const float* __restrict__ bs,       // (10, 3)
    const float* __restrict__ lastW,    // (3, 3)
    const float* __restrict__ lastb,    // (3,)
    const float* __restrict__ cld_ptr,  // workspace scalar (may be null)
    float* __restrict__ out_z,          // (N, 3)
    float* __restrict__ out_ld,         // (N,)
    int N)
{
    __shared__ float lds_af[64 * AF_PAD];   // 15616 B
    __shared__ float lds_x[64 * 3];         // 768 B  -> total 16384 B, 10 blocks/CU

    const int tid = threadIdx.x;
    const int row0 = blockIdx.x * 64;

    // ---- coalesced staging: this block's 64 affine rows = 960 contiguous float4 ----
    // Lane t loads float4 #(k*64+t): each wave-instruction covers 1 KB
    // contiguous, fully consumed -> dense line requests, no L1 reliance.
    const float4* ap = reinterpret_cast<const float4*>(affine) + (size_t)blockIdx.x * 960;
    float4 v[15];
#pragma unroll
    for (int k = 0; k < 15; ++k) v[k] = ap[k * 64 + tid];

    // x for this block: 64 rows * 3 floats = 48 contiguous float4 (one coalesced
    // instruction on lanes 0-47 instead of three stride-12 scalar loads).
    float4 xv;
    if (tid < 48) xv = reinterpret_cast<const float4*>(x)[(size_t)blockIdx.x * 48 + tid];

#pragma unroll
    for (int k = 0; k < 15; ++k) {
        const int idx = k * 64 + tid;       // float4 index within block region
        const int r   = idx / 15;           // local row
        const int e4  = idx - r * 15;       // float4 slot within row
        float* p = &lds_af[r * AF_PAD + e4 * 4];
        p[0] = v[k].x; p[1] = v[k].y; p[2] = v[k].z; p[3] = v[k].w;
    }
    if (tid < 48) {
        float* p = &lds_x[tid * 4];
        p[0] = xv.x; p[1] = xv.y; p[2] = xv.z; p[3] = xv.w;
    }
    __syncthreads();

    const int row = row0 + tid;
    if (row >= N) return;   // N = 2^21 is divisible by 64; guard for safety

    // Uniform log-det constant: one scalar load from workspace (prep kernel),
    // with an in-kernel fallback if no workspace was provided.
    const float cld = cld_ptr ? *cld_ptr : const_logdet(Ws, lastW);

    const float AFFINE_EPS = 1e-4f;

    // lds_x read: bank (3t+c)%32, 2 lanes/bank -> conflict-free.
    float z0 = lds_x[tid * 3 + 0];
    float z1 = lds_x[tid * 3 + 1];
    float z2 = lds_x[tid * 3 + 2];

    const float* af = &lds_af[tid * AF_PAD];
    float ld = 0.0f;

    // Per 2-layer group: one logf of the product of 6 scales instead of 6 logf.
    // Scales are in (1e-4, 1.0001] -> 6-factor product >= 1e-24 >> FLT_MIN.
#pragma unroll
    for (int ii = 0; ii < NUM_LAYERS; ii += 2) {
        float prod = 1.0f;
#pragma unroll
        for (int j = 0; j < 2; ++j) {
            const int i = ii + j;
            const float* W = Ws + i * 9;
            const float* b = bs + i * 3;
            // z = z @ W + b   (out[c] = sum_k z[k] * W[k*3+c] + b[c])
            float n0 = fmaf(z0, W[0], fmaf(z1, W[3], fmaf(z2, W[6], b[0])));
            float n1 = fmaf(z0, W[1], fmaf(z1, W[4], fmaf(z2, W[7], b[1])));
            float n2 = fmaf(z0, W[2], fmaf(z1, W[5], fmaf(z2, W[8], b[2])));

            // sigmoid(s+2) + eps via raw v_exp / v_rcp (~1 ulp; tolerance is 0.25)
            const float sc0 = __builtin_amdgcn_rcpf(1.0f + __expf(-(af[i * 6 + 0] + 2.0f))) + AFFINE_EPS;
            const float sc1 = __builtin_amdgcn_rcpf(1.0f + __expf(-(af[i * 6 + 1] + 2.0f))) + AFFINE_EPS;
            const float sc2 = __builtin_amdgcn_rcpf(1.0f + __expf(-(af[i * 6 + 2] + 2.0f))) + AFFINE_EPS;

            z0 = fmaf(n0, sc0, af[i * 6 + 3]);
            z1 = fmaf(n1, sc1, af[i * 6 + 4]);
            z2 = fmaf(n2, sc2, af[i * 6 + 5]);

            prod *= sc0 * sc1 * sc2;
        }
        ld += __logf(prod);
    }

    // final linear layer
    {
        const float* W = lastW;
        float n0 = fmaf(z0, W[0], fmaf(z1, W[3], fmaf(z2, W[6], lastb[0])));
        float n1 = fmaf(z0, W[1], fmaf(z1, W[4], fmaf(z2, W[7], lastb[1])));
        float n2 = fmaf(z0, W[2], fmaf(z1, W[5], fmaf(z2, W[8], lastb[2])));
        z0 = n0; z1 = n1; z2 = n2;
    }

    // base density: sum_c -0.5*(z_c^2 + log(2*pi)); the log(2*pi) part is in cld
    ld += cld - 0.5f * (z0 * z0 + z1 * z1 + z2 * z2);

    out_z[(size_t)row * 3 + 0] = z0;
    out_z[(size_t)row * 3 + 1] = z1;
    out_z[(size_t)row * 3 + 2] = z2;
    out_ld[row] = ld;
}

extern "C" void kernel_launch(void* const* d_in, const int* in_sizes, int n_in,
                              void* d_out, int out_size, void* d_ws, size_t ws_size,
                              hipStream_t stream) {
    const float* x      = (const float*)d_in[0];
    const float* affine = (const float*)d_in[1];
    const float* Ws     = (const float*)d_in[2];
    const float* bs     = (const float*)d_in[3];
    const float* lastW  = (const float*)d_in[4];
    const float* lastb  = (const float*)d_in[5];

    const int N = in_sizes[0] / 3;

    float* out_z  = (float*)d_out;
    float* out_ld = (float*)d_out + (size_t)N * 3;

    float* cld_ws = (d_ws != nullptr && ws_size >= sizeof(float)) ? (float*)d_ws : nullptr;
    if (cld_ws) {
        prep_kernel<<<1, 1, 0, stream>>>(Ws, lastW, cld_ws);
    }

    const int block = 64;
    const int grid = (N + block - 1) / block;
    flow_kernel<<<grid, block, 0, stream>>>(x, affine, Ws, bs, lastW, lastb,
                                            cld_ws, out_z, out_ld, N);
}